// Round 8
// baseline (54.679 us; speedup 1.0000x reference)
//
#include <hip/hip_runtime.h>

typedef _Float16 f16;
typedef _Float16 f16x2 __attribute__((ext_vector_type(2)));
typedef _Float16 f16x8 __attribute__((ext_vector_type(8)));
typedef float f32x4 __attribute__((ext_vector_type(4)));
typedef unsigned int u32;
typedef unsigned int u32x4 __attribute__((ext_vector_type(4)));

#define AS1 __attribute__((address_space(1)))
#define AS3 __attribute__((address_space(3)))

static __device__ __forceinline__ u32 pk2(float lo, float hi) {
  union { f16 h[2]; u32 u; } v;
  v.h[0] = (f16)lo; v.h[1] = (f16)hi;
  return v.u;
}

// ---- fused prep: blocks 0..2047: W[f,d,e]->fp16 retile;
//      blocks 2048..2111: decayed prefix scan of x -> st (transposed).
// W layout: byte = d*32768 + (e>>5)*8192 + f*64 + ((e>>3)&3)*16 + (e&7)*2
// scan: s[b,0]=0; s[b,t]=(s[b,t-1]+x[b,t-1])/1.2; st[e*8192 + b*2048 + t];
//       64-token chunks, 64-token lookback (1.2^-64 ~ 8.5e-6 rel).
__global__ void k_pre(const float* __restrict__ W, char* __restrict__ wt,
                      const float* __restrict__ x, float* __restrict__ st) {
  int bid = blockIdx.x;
  if (bid < 2048) {
    int t = bid * 256 + threadIdx.x;
    long i = (long)t * 4;                      // 2M W elements, 4/thread
    int f = (int)(i >> 14);
    int k = (int)(i & 16383);
    float4 w4 = *(const float4*)(W + i);
    int d = k >> 7, e = k & 127;
    long byo = (long)d * 32768 + (e >> 5) * 8192 + f * 64 + ((e >> 3) & 3) * 16 + (e & 7) * 2;
    u32* dst = (u32*)(wt + byo);
    dst[0] = pk2(w4.x, w4.y);
    dst[1] = pk2(w4.z, w4.w);
  } else {
    int tid = (bid - 2048) * 256 + threadIdx.x;   // 16384 threads
    int e  = tid & 127;
    int bc = tid >> 7;
    int b  = bc >> 5;
    int ch = bc & 31;
    int t0 = ch * 64;
    const float* xb = x + (long)b * 2048 * 128 + e;
    float* sb = st + (long)e * 8192 + b * 2048;
    const float inv = 1.0f / 1.2f;
    float c = 0.f;
    if (ch > 0) {
      const float* xp = xb + (long)(t0 - 64) * 128;
      #pragma unroll
      for (int t = 0; t < 64; ++t) c = (c + xp[t * 128]) * inv;
    }
    const float* xq = xb + (long)t0 * 128;
    float* sq = sb + t0;
    #pragma unroll
    for (int t = 0; t < 64; ++t) { sq[t] = c; c = (c + xq[t * 128]) * inv; }
  }
}

// ---- final reduce: out = sum over 4 K-split partials (no atomics) ----------
__global__ void k_red(const float4* __restrict__ part, float4* __restrict__ out) {
  int i = blockIdx.x * 256 + threadIdx.x;          // 262144 float4
  float4 a = part[i];
  float4 b = part[i + 262144];
  float4 c = part[i + 524288];
  float4 d = part[i + 786432];
  out[i] = make_float4(a.x + b.x + c.x + d.x, a.y + b.y + c.y + d.y,
                       a.z + b.z + c.z + d.z, a.w + b.w + c.w + d.w);
}

// ---------------- main: part[kq][token,f] = sum_{d in kq} (x*s) W ----------
// grid 256 = 64 token-tiles (BM=128) x K-split 4 -> 1 block/CU. 8 waves =
// f-half(ng) x e-quadrant(ep): DISJOINT W slices -> 256MB L2 traffic.
// B staging: per-wave PRIVATE LDS slots (3 x 4KB) filled by global_load_lds
// DMA, prefetch distance 2, counted s_waitcnt vmcnt(8) (never drains to 0,
// T4); no barriers in the K-loop -> waves self-stagger; consume via
// conflict-free ds_read_b128. This removes the per-lane L1-gather/MSHR
// throttle that pinned R5-R7 at ~25% MfmaUtil.
__global__ __launch_bounds__(512, 2) void k_main(
    const float* __restrict__ x, const float* __restrict__ st,
    const char* __restrict__ wt, float* __restrict__ part) {
  __shared__ __attribute__((aligned(128))) char lds[18432 + 8 * 3 * 4096];
  u32* x_lds  = (u32*)lds;                 // 18.4KB half2(x,x) [128 tok][pad36]
  float* red  = (float*)(lds + 18432);     // 66KB epilogue alias of B slots

  const int tid  = threadIdx.x;
  const int bid  = blockIdx.x;
  const int kq   = bid & 3;          // K-quarter: d in [kq*32, kq*32+32)
  const int tt   = bid >> 2;         // token tile (0..63)
  const int wv   = tid >> 6;         // 0..7
  const int lane = tid & 63;
  const int ng   = wv & 1;           // f half
  const int ep   = wv >> 1;          // e quadrant
  const int r    = lane & 15;
  const int kg   = lane >> 4;
  const int tokenBase = tt * 128;

  // stage x tile as duplicated half2 (xv,xv): [128 tok][32 d], d = kq*32+it
  {
    int row = tid >> 2, c0 = (tid & 3) * 8;
    const float* src = x + (long)(tokenBase + row) * 128 + kq * 32 + c0;
    float4 v0 = *(const float4*)src;
    float4 v1 = *(const float4*)(src + 4);
    u32* dst = &x_lds[row * 36 + c0];
    dst[0] = pk2(v0.x, v0.x); dst[1] = pk2(v0.y, v0.y);
    dst[2] = pk2(v0.z, v0.z); dst[3] = pk2(v0.w, v0.w);
    dst[4] = pk2(v1.x, v1.x); dst[5] = pk2(v1.y, v1.y);
    dst[6] = pk2(v1.z, v1.z); dst[7] = pk2(v1.w, v1.w);
  }

  // s: wave owns e = ep*32 + kg*8 + {0..7} for ALL d; packed half2, 32 VGPRs.
  u32 sreg[8][4];
  {
    const float* stb = st + tokenBase + (long)(ep * 32 + kg * 8) * 8192;
    #pragma unroll
    for (int mr = 0; mr < 8; ++mr)
      #pragma unroll
      for (int jj = 0; jj < 4; ++jj) {
        const float* qp = stb + (long)(2 * jj) * 8192 + mr * 16 + r;
        sreg[mr][jj] = pk2(qp[0], qp[8192]);
      }
  }
  __syncthreads();   // x_lds ready; only barrier before epilogue

  f32x4 acc[8][4];
  #pragma unroll
  for (int mr = 0; mr < 8; ++mr)
    #pragma unroll
    for (int n = 0; n < 4; ++n) acc[mr][n] = (f32x4){0.f, 0.f, 0.f, 0.f};

  const char* wtq = wt + (long)(kq * 32) * 32768 + ep * 8192 + ng * 4096;
  char* bslot = lds + 18432 + wv * 12288;          // this wave's 3 x 4KB slots
  const int lsub = r * 64 + kg * 16;               // lane slot (f row, e group)

  // issue one tile's DMA: 4 x global_load_lds (16B/lane, linear dest)
#define DMA(SLOT, IT)                                                        \
  {                                                                          \
    const char* gs = wtq + (long)(IT) * 32768;                               \
    char* ls = bslot + (SLOT) * 4096;                                        \
    _Pragma("unroll")                                                        \
    for (int q = 0; q < 4; ++q)                                              \
      __builtin_amdgcn_global_load_lds(                                      \
          (const AS1 u32*)(gs + q * 1024 + lane * 16),                       \
          (AS3 u32*)(ls + q * 1024 + lane * 16), 16, 0, 0);                  \
  }
  // one d-step: xb word J (all mr) x B-frags from slot -> 32 MFMAs
#define PHASE(IT, J)                                                         \
  {                                                                          \
    __builtin_amdgcn_sched_barrier(0);                                       \
    int nt = (IT) + 2 > 31 ? 31 : (IT) + 2;                                  \
    DMA(((IT) + 2) % 3, nt);                                                 \
    __asm__ __volatile__("s_waitcnt vmcnt(8)" ::: "memory");                 \
    const char* bs = bslot + ((IT) % 3) * 4096;                              \
    f16x8 bfr[4];                                                            \
    _Pragma("unroll")                                                        \
    for (int n = 0; n < 4; ++n)                                              \
      bfr[n] = *(const f16x8*)(bs + n * 1024 + lsub);                        \
    __builtin_amdgcn_s_setprio(1);                                           \
    _Pragma("unroll")                                                        \
    for (int mr = 0; mr < 8; ++mr) {                                         \
      f16x2 xv2;                                                             \
      *(u32*)&xv2 = xb[mr][J];                                               \
      union { u32 u[4]; f16x8 v; } au;                                       \
      _Pragma("unroll")                                                      \
      for (int jj = 0; jj < 4; ++jj) {                                       \
        f16x2 s2;                                                            \
        *(u32*)&s2 = sreg[mr][jj];                                           \
        f16x2 p = xv2 * s2;                                                  \
        au.u[jj] = *(u32*)&p;                                                \
      }                                                                      \
      _Pragma("unroll")                                                      \
      for (int n = 0; n < 4; ++n)                                            \
        acc[mr][n] = __builtin_amdgcn_mfma_f32_16x16x32_f16(                 \
            au.v, bfr[n], acc[mr][n], 0, 0, 0);                              \
    }                                                                        \
    __builtin_amdgcn_s_setprio(0);                                           \
  }

  DMA(0, 0);
  DMA(1, 1);

  #pragma unroll 1
  for (int it4 = 0; it4 < 8; ++it4) {
    // batched x: one ds_read_b128 per mr covers 4 d-steps
    u32x4 xb[8];
    #pragma unroll
    for (int mr = 0; mr < 8; ++mr)
      xb[mr] = *(const u32x4*)&x_lds[(mr * 16 + r) * 36 + it4 * 4];
    int it = it4 * 4;
    PHASE(it, 0);
    PHASE(it + 1, 1);
    PHASE(it + 2, 2);
    PHASE(it + 3, 3);
  }
#undef PHASE
#undef DMA

  // epilogue: reduce the 4 e-quadrant waves (per f-half) in LDS, then store
  __syncthreads();
  #pragma unroll
  for (int round = 0; round < 4; ++round) {
    if (ep == round) {
      #pragma unroll
      for (int mr = 0; mr < 8; ++mr)
        #pragma unroll
        for (int n = 0; n < 4; ++n)
          #pragma unroll
          for (int q2 = 0; q2 < 4; ++q2) {
            // C/D: col=lane&15 (f), row=kg*4+reg (token)
            int idx = (mr * 16 + kg * 4 + q2) * 129 + ng * 64 + n * 16 + r;
            if (round == 0) red[idx] = acc[mr][n][q2];
            else            red[idx] += acc[mr][n][q2];
          }
    }
    __syncthreads();
  }
  // plain coalesced stores to this kq's private partial slice
  float* outp = part + (long)kq * 1048576 + (long)tokenBase * 128;
  #pragma unroll
  for (int j = 0; j < 32; ++j) {
    int row = (tid >> 7) + j * 4;
    int col = tid & 127;
    outp[row * 128 + col] = red[row * 129 + col];
  }
}

extern "C" void kernel_launch(void* const* d_in, const int* in_sizes, int n_in,
                              void* d_out, int out_size, void* d_ws, size_t ws_size,
                              hipStream_t stream) {
  const float* x = (const float*)d_in[0];        // [4,2048,128] f32
  const float* W = (const float*)d_in[1];        // [128,128,128] f32
  float* out  = (float*)d_out;                   // [4,2048,128] f32
  float* st   = (float*)d_ws;                    // 4 MB: s transposed [e][token]
  char*  wt   = (char*)d_ws + (4 << 20);         // 4 MB: W fp16 retiled
  float* part = (float*)((char*)d_ws + (8 << 20)); // 16 MB: K-split partials

  k_pre <<<dim3(2112), dim3(256), 0, stream>>>(W, wt, x, st);
  k_main<<<dim3(256),  dim3(512), 0, stream>>>(x, st, wt, part);
  k_red <<<dim3(1024), dim3(256), 0, stream>>>((const float4*)part, (float4*)out);
}